// Round 12
// baseline (239.947 us; speedup 1.0000x reference)
//
#include <hip/hip_runtime.h>
#include <stdint.h>

#define NB 4
#define NS 2048
#define ND 1024
#define NH 16
#define NDK 64
#define NM (NB*NS)   // 8192 rows total

typedef __attribute__((ext_vector_type(8))) short short8;
typedef __attribute__((ext_vector_type(8))) unsigned short ushort8v;
typedef __attribute__((ext_vector_type(4))) unsigned short ushort4v;
typedef __attribute__((ext_vector_type(4))) float f32x4;
typedef __attribute__((ext_vector_type(16))) float f32x16;

__device__ __forceinline__ unsigned short f2bf(float f) {
  union { float f; uint32_t u; } v; v.f = f;
  uint32_t u = v.u;
  return (unsigned short)((u + 0x7FFFu + ((u >> 16) & 1u)) >> 16);
}

__device__ __forceinline__ void gload16(const void* g, void* l) {
  __builtin_amdgcn_global_load_lds(
      (const __attribute__((address_space(1))) void*)g,
      (__attribute__((address_space(3))) void*)l, 16, 0, 0);
}

// T1: bijective XCD swizzle (requires nwg % 8 == 0)
__device__ __forceinline__ int xcd_swz(int flat, int nwg) {
  return (flat & 7) * (nwg >> 3) + (flat >> 3);
}

// ---------------- fused conversion fp32 -> bf16 (q,k,v + 4 weights) ----------------
__global__ void convert_all(
    const float* __restrict__ x0, const float* __restrict__ x1, const float* __restrict__ x2,
    const float* __restrict__ w0, const float* __restrict__ w1,
    const float* __restrict__ w2, const float* __restrict__ w3,
    unsigned short* __restrict__ ox0, unsigned short* __restrict__ ox1, unsigned short* __restrict__ ox2,
    unsigned short* __restrict__ ow0, unsigned short* __restrict__ ow1,
    unsigned short* __restrict__ ow2, unsigned short* __restrict__ ow3)
{
  const float* src;
  unsigned short* dst;
  size_t i;
  if (blockIdx.y < 3) {
    src = blockIdx.y == 0 ? x0 : (blockIdx.y == 1 ? x1 : x2);
    dst = blockIdx.y == 0 ? ox0 : (blockIdx.y == 1 ? ox1 : ox2);
    i = ((size_t)blockIdx.x * 256 + threadIdx.x) * 8;
  } else {
    if (blockIdx.x >= 2048) return;
    size_t e = ((size_t)blockIdx.x * 256 + threadIdx.x) * 8;
    int which = (int)(e >> 20);
    size_t off = e & ((1u << 20) - 1);
    const float* ws[4] = {w0, w1, w2, w3};
    unsigned short* wd[4] = {ow0, ow1, ow2, ow3};
    src = ws[which]; dst = wd[which]; i = off;
  }
  f32x4 a = *(const f32x4*)(src + i);
  f32x4 b = *(const f32x4*)(src + i + 4);
  ushort8v h;
  h[0]=f2bf(a.x); h[1]=f2bf(a.y); h[2]=f2bf(a.z); h[3]=f2bf(a.w);
  h[4]=f2bf(b.x); h[5]=f2bf(b.y); h[6]=f2bf(b.z); h[7]=f2bf(b.w);
  *(ushort8v*)(dst + i) = h;
}

// ================== 256xBN deep-pipelined GEMM (8 waves, BK=64) ==================
#define GPHASE(MH, NH, LA, LB)                                                 \
  {                                                                            \
    if (LA) {                                                                  \
      _Pragma("unroll") for (int mm = 0; mm < 4; ++mm)                         \
        _Pragma("unroll") for (int kk = 0; kk < 2; ++kk)                       \
          af[mm][kk] = *(const short8*)(Ab + (MH)*8192 + mm*2048 + rowb + aoff[kk]); \
    }                                                                          \
    if (LB) {                                                                  \
      _Pragma("unroll") for (int nn = 0; nn < NN; ++nn)                        \
        _Pragma("unroll") for (int kk = 0; kk < 2; ++kk)                       \
          bf[nn][kk] = *(const short8*)(Bb + (NH)*(NN*2048) + nn*2048 + rowb + aoff[kk]); \
    }                                                                          \
    __builtin_amdgcn_s_barrier();                                              \
    __builtin_amdgcn_s_setprio(1);                                             \
    _Pragma("unroll") for (int mm = 0; mm < 4; ++mm)                           \
      _Pragma("unroll") for (int nn = 0; nn < NN; ++nn)                        \
        _Pragma("unroll") for (int kk = 0; kk < 2; ++kk)                       \
          acc[(MH)*4+mm][(NH)*NN+nn] = __builtin_amdgcn_mfma_f32_16x16x32_bf16( \
              af[mm][kk], bf[nn][kk], acc[(MH)*4+mm][(NH)*NN+nn], 0, 0, 0);    \
    __builtin_amdgcn_s_setprio(0);                                             \
    __builtin_amdgcn_s_barrier();                                              \
  }

template<int OUT, int PRESCALE, int BN>
__device__ __forceinline__ void gemm256_core(
    const unsigned short* __restrict__ A,
    const unsigned short* __restrict__ Bt,
    void* __restrict__ Cout,
    unsigned short* lds, int m0, int n0)
{
  const int K = ND, N = ND;
  const int NN = BN / 128;
  const int NBL = BN / 64;
  const int ASZ = 16384, BSZ = BN * 64, SZ = ASZ + BSZ;
  const int tid = threadIdx.x;
  const int lane = tid & 63, wid = tid >> 6;
  const int l15 = lane & 15, lg = lane >> 4;
  const int wr = wid >> 2, wc = wid & 3;
  const float QSC = 0.125f * 1.44269504088896f;

  const unsigned short* Asrc[4];
  const unsigned short* Bsrc[NBL];
#pragma unroll
  for (int l = 0; l < 4; ++l) {
    int cidx = l*512 + tid;
    int r = cidx >> 3;
    int cs = ((cidx & 7) ^ (r & 7)) * 8;
    Asrc[l] = A + (size_t)(m0 + r)*K + cs;
  }
#pragma unroll
  for (int l = 0; l < NBL; ++l) {
    int cidx = l*512 + tid;
    int r = cidx >> 3;
    int cs = ((cidx & 7) ^ (r & 7)) * 8;
    Bsrc[l] = Bt + (size_t)(n0 + r)*K + cs;
  }

  const int rowb = l15 * 128;
  int aoff[2];
  aoff[0] = ((lg)     ^ (l15 & 7)) * 16;
  aoff[1] = ((4 + lg) ^ (l15 & 7)) * 16;

  f32x4 acc[8][2*NN] = {};
  short8 af[4][2], bf[NN][2];

#pragma unroll
  for (int l = 0; l < 4; ++l) gload16(Asrc[l], lds + l*4096 + tid*8);
#pragma unroll
  for (int l = 0; l < NBL; ++l) gload16(Bsrc[l], lds + ASZ + l*4096 + tid*8);
  asm volatile("s_waitcnt vmcnt(0)" ::: "memory");
  __builtin_amdgcn_s_barrier();

  const int NT = K / 64;   // 16
  for (int t = 0; t < NT; ++t) {
    const int cur = t & 1;
    if (t + 1 < NT) {
      unsigned short* dst = lds + (cur^1)*SZ;
#pragma unroll
      for (int l = 0; l < 4; ++l) gload16(Asrc[l] + (t+1)*64, dst + l*4096 + tid*8);
#pragma unroll
      for (int l = 0; l < NBL; ++l) gload16(Bsrc[l] + (t+1)*64, dst + ASZ + l*4096 + tid*8);
    }
    const char* Ab = (const char*)(lds + cur*SZ) + wr*16384;
    const char* Bb = (const char*)(lds + cur*SZ + ASZ) + wc*(BN*32);

    GPHASE(0, 0, 1, 1)
    GPHASE(0, 1, 0, 1)
    GPHASE(1, 1, 1, 0)
    GPHASE(1, 0, 0, 1)

    asm volatile("s_waitcnt vmcnt(0)" ::: "memory");
    __builtin_amdgcn_s_barrier();
  }

#pragma unroll
  for (int m = 0; m < 8; ++m)
#pragma unroll
    for (int n = 0; n < 2*NN; ++n)
#pragma unroll
      for (int i = 0; i < 4; ++i) {
        int row = m0 + wr*128 + m*16 + lg*4 + i;
        int col = n0 + wc*(BN/4) + n*16 + l15;
        float val = PRESCALE ? acc[m][n][i] * QSC : acc[m][n][i];
        if (OUT == 0)
          ((float*)Cout)[(size_t)row * N + col] = val;
        else if (OUT == 1)
          ((unsigned short*)Cout)[(size_t)row * N + col] = f2bf(val);
        else
          ((unsigned short*)Cout)[((size_t)((row >> 11)*1024 + col))*NS + (row & (NS-1))]
              = f2bf(val);
      }
}

// NOTE launch_bounds: 2nd arg behaves as BLOCKS/CU here (R10 evidence: (512,4)
// capped VGPR at 64 = 32 waves/CU). LDS already limits these to 1 block/CU, so
// (512,1) -> 256-VGPR cap; acc[8][4]+frags ~180 regs now fits without spill.
__global__ __launch_bounds__(512, 1) void gemm_qkv(
    const unsigned short* __restrict__ Xq, const unsigned short* __restrict__ Wq, unsigned short* Qb,
    const unsigned short* __restrict__ Xk, const unsigned short* __restrict__ Wk, unsigned short* Kb,
    const unsigned short* __restrict__ Xv, const unsigned short* __restrict__ Wv, unsigned short* VbT)
{
  __shared__ unsigned short lds[65536];   // 128 KB
  int flat = (blockIdx.z * 32 + blockIdx.y) * 4 + blockIdx.x;
  int swz = xcd_swz(flat, 384);
  int z = swz >> 7, rem = swz & 127;
  int m0 = (rem >> 2) * 256, n0 = (rem & 3) * 256;
  if (z == 0)      gemm256_core<1,1,256>(Xq, Wq, Qb,  lds, m0, n0);
  else if (z == 1) gemm256_core<1,0,256>(Xk, Wk, Kb,  lds, m0, n0);
  else             gemm256_core<2,0,256>(Xv, Wv, VbT, lds, m0, n0);
}

__global__ __launch_bounds__(512, 1) void gemm_o(
    const unsigned short* __restrict__ A, const unsigned short* __restrict__ Bt, float* C)
{
  __shared__ unsigned short lds[49152];   // 96 KB
  int flat = blockIdx.y * 8 + blockIdx.x;
  int swz = xcd_swz(flat, 256);
  gemm256_core<0,0,128>(A, Bt, C, lds, (swz >> 3) * 256, (swz & 7) * 128);
}

// ---------------- Flash attention v11: split-KV wave-groups, fixed VGPR cap ----------
// grid: (S/256, B*H) -> 512 blocks, 512 threads = 2 wave-groups x 4 waves.
// Group g handles KV tiles [g*16, g*16+16) for the SAME 256 q-rows (own K/V
// dbuf). No-max softmax => partials purely additive; combine via dead K/V LDS.
// 16 waves/CU (2 blocks/CU). launch_bounds (512,2): 2 blocks/CU -> 128-VGPR
// cap; loop state measured ~96 regs (R11) -> fits, unlike R10's (512,4)=64-cap
// spill storm. Per wave: 64 q (2 q-sets amortize each kf/vf read).
__global__ __launch_bounds__(512, 2) void flash_attn(
    const unsigned short* __restrict__ Qb,   // pre-scaled by 0.125*log2e
    const unsigned short* __restrict__ Kb,
    const unsigned short* __restrict__ VT,   // [B*H*64][2048] = V^T per head
    unsigned short* __restrict__ O)          // bf16 [8192][1024]
{
  __shared__ unsigned short Kt[2][2][64*64]; // [grp][buf], 8KB each -> 32KB
  __shared__ unsigned short Vt[2][2][64*64]; // 32KB
  const int tid = threadIdx.x, lane = tid & 63, wid = tid >> 6;
  const int l31 = lane & 31, hi = lane >> 5;
  const int grp = wid >> 2, widl = wid & 3;
  const int ltid = tid & 255;
  int flat = blockIdx.y * 8 + blockIdx.x;
  int swz = xcd_swz(flat, 512);
  const int bh = swz >> 3, b = bh >> 4, h = bh & 15;
  const int q0 = (swz & 7) * 256 + widl * 64;

  // staging for this group's KV half
  const unsigned short* Kp[2]; const unsigned short* Vp[2]; int dofs[2];
#pragma unroll
  for (int p = 0; p < 2; ++p) {
    int slot = ltid + p*256;
    int g = slot >> 6, r = slot & 63;
    Kp[p] = Kb + ((size_t)(b*NS + grp*1024 + r))*ND + h*64 + g*8;
    Vp[p] = VT + ((size_t)(bh*64 + r))*NS + grp*1024 + g*8;
    dofs[p] = slot * 8;
  }

  // Q frags (B-operand), 2 q-sets: col = q = qs*32 + l31, k = ks*16 + hi*8 + j
  short8 qf[2][4];
#pragma unroll
  for (int qs = 0; qs < 2; ++qs)
#pragma unroll
    for (int ks = 0; ks < 4; ++ks)
      qf[qs][ks] = *(const short8*)(Qb + (size_t)(b*NS + q0 + qs*32 + l31)*ND + h*64 + ks*16 + hi*8);

  f32x16 oacc[2][2] = {};    // [qs][dblk]; C rows q=(r&3)+8(r>>2)+4hi, col d=dblk*32+l31
  float lsum[2] = {0.f, 0.f};

  unsigned short* Ktg = &Kt[grp][0][0];
  unsigned short* Vtg = &Vt[grp][0][0];

#pragma unroll
  for (int p = 0; p < 2; ++p) {
    gload16(Kp[p], Ktg + dofs[p]);
    gload16(Vp[p], Vtg + dofs[p]);
  }
  __syncthreads();

  for (int t = 0; t < 16; ++t) {
    const int cur = t & 1;
    if (t + 1 < 16) {
#pragma unroll
      for (int p = 0; p < 2; ++p) {
        gload16(Kp[p] + (size_t)(t+1)*64*ND, Ktg + (cur^1)*4096 + dofs[p]);
        gload16(Vp[p] + (t+1)*64,            Vtg + (cur^1)*4096 + dofs[p]);
      }
    }
    const char* Kc = (const char*)(Ktg + cur*4096);
    const char* Vc = (const char*)(Vtg + cur*4096);

    short8 pa[2][2][2];      // [qs][n][ksl]
    float rs[2] = {0.f, 0.f};

#pragma unroll
    for (int n = 0; n < 2; ++n) {
      f32x16 st[2] = {};
      const int r = n*32 + l31;
      __builtin_amdgcn_s_setprio(1);
#pragma unroll
      for (int ks = 0; ks < 4; ++ks) {
        short8 kf = *(const short8*)(Kc + (((2*ks + hi) << 10) + r*16));
        st[0] = __builtin_amdgcn_mfma_f32_32x32x16_bf16(kf, qf[0][ks], st[0], 0, 0, 0);
        st[1] = __builtin_amdgcn_mfma_f32_32x32x16_bf16(kf, qf[1][ks], st[1], 0, 0, 0);
      }
      __builtin_amdgcn_s_setprio(0);
#pragma unroll
      for (int qs = 0; qs < 2; ++qs) {
        float lrs = 0.f;
#pragma unroll
        for (int e = 0; e < 16; ++e) {
          float p = __builtin_amdgcn_exp2f(st[qs][e]);
          st[qs][e] = p;
          lrs += p;
        }
        rs[qs] += lrs;
        uint32_t w[4][2];
#pragma unroll
        for (int e = 0; e < 4; ++e) {
          asm("v_cvt_pk_bf16_f32 %0, %1, %2"
              : "=v"(w[e][0]) : "v"(st[qs][4*e+0]), "v"(st[qs][4*e+1]));
          asm("v_cvt_pk_bf16_f32 %0, %1, %2"
              : "=v"(w[e][1]) : "v"(st[qs][4*e+2]), "v"(st[qs][4*e+3]));
        }
#pragma unroll
        for (int ksl = 0; ksl < 2; ++ksl) {
          uint32_t a0 = w[2*ksl][0], b0 = w[2*ksl+1][0];
          uint32_t a1 = w[2*ksl][1], b1 = w[2*ksl+1][1];
          asm("v_permlane32_swap_b32 %0, %1" : "+v"(a0), "+v"(b0));
          asm("v_permlane32_swap_b32 %0, %1" : "+v"(a1), "+v"(b1));
          union { uint32_t u[4]; short8 s; } f;
          f.u[0] = a0; f.u[1] = a1; f.u[2] = b0; f.u[3] = b1;
          pa[qs][n][ksl] = f.s;
        }
      }
    }
#pragma unroll
    for (int qs = 0; qs < 2; ++qs) {
      rs[qs] += __shfl_xor(rs[qs], 32);
      lsum[qs] += rs[qs];
    }

    __builtin_amdgcn_s_setprio(1);
#pragma unroll
    for (int d = 0; d < 2; ++d) {
      const int dr = d*32 + l31;
#pragma unroll
      for (int n = 0; n < 2; ++n)
#pragma unroll
        for (int ksl = 0; ksl < 2; ++ksl) {
          const int g = n*4 + ksl*2 + hi;
          short8 vf = *(const short8*)(Vc + ((g << 10) + dr*16));
          oacc[0][d] = __builtin_amdgcn_mfma_f32_32x32x16_bf16(pa[0][n][ksl], vf, oacc[0][d], 0, 0, 0);
          oacc[1][d] = __builtin_amdgcn_mfma_f32_32x32x16_bf16(pa[1][n][ksl], vf, oacc[1][d], 0, 0, 0);
        }
    }
    __builtin_amdgcn_s_setprio(0);
    __syncthreads();   // next tile staged AND buf[cur] free (both groups)
  }

  // ---- combine partials: group1 -> LDS -> group0 adds, normalizes, stores ----
  float* lsq = (float*)&Vt[0][0][0];               // 2 KB (V buffers dead)
  if (grp == 1) {
    lsq[(widl*64 + lane)*2 + 0] = lsum[0];
    lsq[(widl*64 + lane)*2 + 1] = lsum[1];
  }
  __syncthreads();
  if (grp == 0) {
    lsum[0] += lsq[(widl*64 + lane)*2 + 0];
    lsum[1] += lsq[(widl*64 + lane)*2 + 1];
  }

  f32x16* obuf = (f32x16*)&Kt[0][0][0];            // 32 KB (K buffers dead)
#pragma unroll
  for (int d = 0; d < 2; ++d) {
    if (grp == 1) {
      obuf[(widl*64 + lane)*2 + 0] = oacc[0][d];
      obuf[(widl*64 + lane)*2 + 1] = oacc[1][d];
    }
    __syncthreads();
    if (grp == 0) {
#pragma unroll
      for (int qs = 0; qs < 2; ++qs) {
        f32x16 o2 = obuf[(widl*64 + lane)*2 + qs];
#pragma unroll
        for (int r = 0; r < 16; ++r) {
          float li = 1.0f / __shfl(lsum[qs], (r & 3) + 8*(r >> 2) + 4*hi);
          int qrow = q0 + qs*32 + (r & 3) + 8*(r >> 2) + 4*hi;
          O[(size_t)(b*NS + qrow)*ND + h*64 + d*32 + l31]
              = f2bf((oacc[qs][d][r] + o2[r]) * li);
        }
      }
    }
    __syncthreads();
  }
}

// ---------------- launch ----------------
extern "C" void kernel_launch(void* const* d_in, const int* in_sizes, int n_in,
                              void* d_out, int out_size, void* d_ws, size_t ws_size,
                              hipStream_t stream) {
  const float* q  = (const float*)d_in[0];
  const float* k  = (const float*)d_in[1];
  const float* v  = (const float*)d_in[2];
  const float* wq = (const float*)d_in[3];
  const float* wk = (const float*)d_in[4];
  const float* wv = (const float*)d_in[5];
  const float* wo = (const float*)d_in[6];

  unsigned short* Wq = (unsigned short*)d_ws;
  unsigned short* Wk = Wq + (size_t)ND*ND;
  unsigned short* Wv = Wk + (size_t)ND*ND;
  unsigned short* Wo = Wv + (size_t)ND*ND;
  unsigned short* Xq = Wo + (size_t)ND*ND;
  unsigned short* Xk = Xq + (size_t)NM*ND;
  unsigned short* Xv = Xk + (size_t)NM*ND;
  unsigned short* Qb = Xv + (size_t)NM*ND;
  unsigned short* Kb = Qb + (size_t)NM*ND;
  unsigned short* VbT = (unsigned short*)d_out;   // scratch in d_out; rewritten by gemm_o
  unsigned short* Ob  = Xq;                       // alias: Xq dead after qkv launch

  convert_all<<<dim3(NM*ND/(256*8), 4), 256, 0, stream>>>(
      q, k, v, wq, wk, wv, wo, Xq, Xk, Xv, Wq, Wk, Wv, Wo);

  gemm_qkv<<<dim3(4, 32, 3), 512, 0, stream>>>(Xq, Wq, Qb, Xk, Wk, Kb, Xv, Wv, VbT);

  flash_attn<<<dim3(8, 64), 512, 0, stream>>>(Qb, Kb, VbT, Ob);

  gemm_o<<<dim3(8, 32), 512, 0, stream>>>(Ob, Wo, (float*)d_out);
}

// Round 13
// 207.282 us; speedup vs baseline: 1.1576x; 1.1576x over previous
//
#include <hip/hip_runtime.h>
#include <stdint.h>

#define NB 4
#define NS 2048
#define ND 1024
#define NH 16
#define NDK 64
#define NM (NB*NS)   // 8192 rows total

typedef __attribute__((ext_vector_type(8))) short short8;
typedef __attribute__((ext_vector_type(8))) unsigned short ushort8v;
typedef __attribute__((ext_vector_type(4))) unsigned short ushort4v;
typedef __attribute__((ext_vector_type(4))) float f32x4;
typedef __attribute__((ext_vector_type(16))) float f32x16;

__device__ __forceinline__ unsigned short f2bf(float f) {
  union { float f; uint32_t u; } v; v.f = f;
  uint32_t u = v.u;
  return (unsigned short)((u + 0x7FFFu + ((u >> 16) & 1u)) >> 16);
}

__device__ __forceinline__ void gload16(const void* g, void* l) {
  __builtin_amdgcn_global_load_lds(
      (const __attribute__((address_space(1))) void*)g,
      (__attribute__((address_space(3))) void*)l, 16, 0, 0);
}

// T1: bijective XCD swizzle (requires nwg % 8 == 0)
__device__ __forceinline__ int xcd_swz(int flat, int nwg) {
  return (flat & 7) * (nwg >> 3) + (flat >> 3);
}

// ---------------- fused conversion fp32 -> bf16 (q,k,v + 4 weights) ----------------
__global__ void convert_all(
    const float* __restrict__ x0, const float* __restrict__ x1, const float* __restrict__ x2,
    const float* __restrict__ w0, const float* __restrict__ w1,
    const float* __restrict__ w2, const float* __restrict__ w3,
    unsigned short* __restrict__ ox0, unsigned short* __restrict__ ox1, unsigned short* __restrict__ ox2,
    unsigned short* __restrict__ ow0, unsigned short* __restrict__ ow1,
    unsigned short* __restrict__ ow2, unsigned short* __restrict__ ow3)
{
  const float* src;
  unsigned short* dst;
  size_t i;
  if (blockIdx.y < 3) {
    src = blockIdx.y == 0 ? x0 : (blockIdx.y == 1 ? x1 : x2);
    dst = blockIdx.y == 0 ? ox0 : (blockIdx.y == 1 ? ox1 : ox2);
    i = ((size_t)blockIdx.x * 256 + threadIdx.x) * 8;
  } else {
    if (blockIdx.x >= 2048) return;
    size_t e = ((size_t)blockIdx.x * 256 + threadIdx.x) * 8;
    int which = (int)(e >> 20);
    size_t off = e & ((1u << 20) - 1);
    const float* ws[4] = {w0, w1, w2, w3};
    unsigned short* wd[4] = {ow0, ow1, ow2, ow3};
    src = ws[which]; dst = wd[which]; i = off;
  }
  f32x4 a = *(const f32x4*)(src + i);
  f32x4 b = *(const f32x4*)(src + i + 4);
  ushort8v h;
  h[0]=f2bf(a.x); h[1]=f2bf(a.y); h[2]=f2bf(a.z); h[3]=f2bf(a.w);
  h[4]=f2bf(b.x); h[5]=f2bf(b.y); h[6]=f2bf(b.z); h[7]=f2bf(b.w);
  *(ushort8v*)(dst + i) = h;
}

// ================== 256xBN deep-pipelined GEMM (8 waves, BK=64) ==================
#define GPHASE(MH, NH, LA, LB)                                                 \
  {                                                                            \
    if (LA) {                                                                  \
      _Pragma("unroll") for (int mm = 0; mm < 4; ++mm)                         \
        _Pragma("unroll") for (int kk = 0; kk < 2; ++kk)                       \
          af[mm][kk] = *(const short8*)(Ab + (MH)*8192 + mm*2048 + rowb + aoff[kk]); \
    }                                                                          \
    if (LB) {                                                                  \
      _Pragma("unroll") for (int nn = 0; nn < NN; ++nn)                        \
        _Pragma("unroll") for (int kk = 0; kk < 2; ++kk)                       \
          bf[nn][kk] = *(const short8*)(Bb + (NH)*(NN*2048) + nn*2048 + rowb + aoff[kk]); \
    }                                                                          \
    __builtin_amdgcn_s_barrier();                                              \
    __builtin_amdgcn_s_setprio(1);                                             \
    _Pragma("unroll") for (int mm = 0; mm < 4; ++mm)                           \
      _Pragma("unroll") for (int nn = 0; nn < NN; ++nn)                        \
        _Pragma("unroll") for (int kk = 0; kk < 2; ++kk)                       \
          acc[(MH)*4+mm][(NH)*NN+nn] = __builtin_amdgcn_mfma_f32_16x16x32_bf16( \
              af[mm][kk], bf[nn][kk], acc[(MH)*4+mm][(NH)*NN+nn], 0, 0, 0);    \
    __builtin_amdgcn_s_setprio(0);                                             \
    __builtin_amdgcn_s_barrier();                                              \
  }

template<int OUT, int PRESCALE, int BN>
__device__ __forceinline__ void gemm256_core(
    const unsigned short* __restrict__ A,
    const unsigned short* __restrict__ Bt,
    void* __restrict__ Cout,
    unsigned short* lds, int m0, int n0)
{
  const int K = ND, N = ND;
  const int NN = BN / 128;
  const int NBL = BN / 64;
  const int ASZ = 16384, BSZ = BN * 64, SZ = ASZ + BSZ;
  const int tid = threadIdx.x;
  const int lane = tid & 63, wid = tid >> 6;
  const int l15 = lane & 15, lg = lane >> 4;
  const int wr = wid >> 2, wc = wid & 3;
  const float QSC = 0.125f * 1.44269504088896f;

  const unsigned short* Asrc[4];
  const unsigned short* Bsrc[NBL];
#pragma unroll
  for (int l = 0; l < 4; ++l) {
    int cidx = l*512 + tid;
    int r = cidx >> 3;
    int cs = ((cidx & 7) ^ (r & 7)) * 8;
    Asrc[l] = A + (size_t)(m0 + r)*K + cs;
  }
#pragma unroll
  for (int l = 0; l < NBL; ++l) {
    int cidx = l*512 + tid;
    int r = cidx >> 3;
    int cs = ((cidx & 7) ^ (r & 7)) * 8;
    Bsrc[l] = Bt + (size_t)(n0 + r)*K + cs;
  }

  const int rowb = l15 * 128;
  int aoff[2];
  aoff[0] = ((lg)     ^ (l15 & 7)) * 16;
  aoff[1] = ((4 + lg) ^ (l15 & 7)) * 16;

  f32x4 acc[8][2*NN] = {};
  short8 af[4][2], bf[NN][2];

#pragma unroll
  for (int l = 0; l < 4; ++l) gload16(Asrc[l], lds + l*4096 + tid*8);
#pragma unroll
  for (int l = 0; l < NBL; ++l) gload16(Bsrc[l], lds + ASZ + l*4096 + tid*8);
  asm volatile("s_waitcnt vmcnt(0)" ::: "memory");
  __builtin_amdgcn_s_barrier();

  const int NT = K / 64;   // 16
  for (int t = 0; t < NT; ++t) {
    const int cur = t & 1;
    if (t + 1 < NT) {
      unsigned short* dst = lds + (cur^1)*SZ;
#pragma unroll
      for (int l = 0; l < 4; ++l) gload16(Asrc[l] + (t+1)*64, dst + l*4096 + tid*8);
#pragma unroll
      for (int l = 0; l < NBL; ++l) gload16(Bsrc[l] + (t+1)*64, dst + ASZ + l*4096 + tid*8);
    }
    const char* Ab = (const char*)(lds + cur*SZ) + wr*16384;
    const char* Bb = (const char*)(lds + cur*SZ + ASZ) + wc*(BN*32);

    GPHASE(0, 0, 1, 1)
    GPHASE(0, 1, 0, 1)
    GPHASE(1, 1, 1, 0)
    GPHASE(1, 0, 0, 1)

    asm volatile("s_waitcnt vmcnt(0)" ::: "memory");
    __builtin_amdgcn_s_barrier();
  }

#pragma unroll
  for (int m = 0; m < 8; ++m)
#pragma unroll
    for (int n = 0; n < 2*NN; ++n)
#pragma unroll
      for (int i = 0; i < 4; ++i) {
        int row = m0 + wr*128 + m*16 + lg*4 + i;
        int col = n0 + wc*(BN/4) + n*16 + l15;
        float val = PRESCALE ? acc[m][n][i] * QSC : acc[m][n][i];
        if (OUT == 0)
          ((float*)Cout)[(size_t)row * N + col] = val;
        else if (OUT == 1)
          ((unsigned short*)Cout)[(size_t)row * N + col] = f2bf(val);
        else
          ((unsigned short*)Cout)[((size_t)((row >> 11)*1024 + col))*NS + (row & (NS-1))]
              = f2bf(val);
      }
}

__global__ __launch_bounds__(512, 2) void gemm_qkv(
    const unsigned short* __restrict__ Xq, const unsigned short* __restrict__ Wq, unsigned short* Qb,
    const unsigned short* __restrict__ Xk, const unsigned short* __restrict__ Wk, unsigned short* Kb,
    const unsigned short* __restrict__ Xv, const unsigned short* __restrict__ Wv, unsigned short* VbT)
{
  __shared__ unsigned short lds[65536];   // 128 KB
  int flat = (blockIdx.z * 32 + blockIdx.y) * 4 + blockIdx.x;
  int swz = xcd_swz(flat, 384);
  int z = swz >> 7, rem = swz & 127;
  int m0 = (rem >> 2) * 256, n0 = (rem & 3) * 256;
  if (z == 0)      gemm256_core<1,1,256>(Xq, Wq, Qb,  lds, m0, n0);
  else if (z == 1) gemm256_core<1,0,256>(Xk, Wk, Kb,  lds, m0, n0);
  else             gemm256_core<2,0,256>(Xv, Wv, VbT, lds, m0, n0);
}

__global__ __launch_bounds__(512, 2) void gemm_o(
    const unsigned short* __restrict__ A, const unsigned short* __restrict__ Bt, float* C)
{
  __shared__ unsigned short lds[49152];   // 96 KB
  int flat = blockIdx.y * 8 + blockIdx.x;
  int swz = xcd_swz(flat, 256);
  gemm256_core<0,0,128>(A, Bt, C, lds, (swz >> 3) * 256, (swz & 7) * 128);
}

// ---------------- Flash attention v12: R9 structure + 3-buf counted vmcnt (T4) ----
// grid: (S/256, B*H) -> 512 blocks, 256 thr, 4 waves x 64 q (2 q-sets share
// K/V frag reads). THREE KV buffers (48 KB): tile t+2 issued at top of iter t;
// end-of-iter wait is s_waitcnt vmcnt(4) (t+1 landed, t+2 stays in flight)
// + raw s_barrier — per-wave count before barrier makes it block-wide (m218
// pattern). Tail: t=30 drains vmcnt(0); t=31 computes without barrier.
// Group-major conflict-free tiles; exact no-max softmax; in-register P.
__global__ __launch_bounds__(256, 2) void flash_attn(
    const unsigned short* __restrict__ Qb,   // pre-scaled by 0.125*log2e
    const unsigned short* __restrict__ Kb,
    const unsigned short* __restrict__ VT,   // [B*H*64][2048] = V^T per head
    unsigned short* __restrict__ O)          // bf16 [8192][1024]
{
  __shared__ unsigned short Kt[3][64*64];    // [buf][g=d-group][s-row][8] : 24KB
  __shared__ unsigned short Vt[3][64*64];    // 24KB
  const int tid = threadIdx.x, lane = tid & 63, wid = tid >> 6;
  const int l31 = lane & 31, hi = lane >> 5;
  int flat = blockIdx.y * 8 + blockIdx.x;
  int swz = xcd_swz(flat, 512);
  const int bh = swz >> 3, b = bh >> 4, h = bh & 15;
  const int q0 = (swz & 7) * 256 + wid * 64;

  // staging: slot in [0,512) 16B-chunks; g = slot>>6, r = slot&63; linear dest.
  const unsigned short* Kp[2]; const unsigned short* Vp[2]; int dofs[2];
#pragma unroll
  for (int p = 0; p < 2; ++p) {
    int slot = tid + p*256;
    int g = slot >> 6, r = slot & 63;
    Kp[p] = Kb + ((size_t)(b*NS + r))*ND + h*64 + g*8;
    Vp[p] = VT + ((size_t)(bh*64 + r))*NS + g*8;
    dofs[p] = slot * 8;
  }

  // Q frags (B-operand), 2 q-sets: col = q = qs*32 + l31, k = ks*16 + hi*8 + j
  short8 qf[2][4];
#pragma unroll
  for (int qs = 0; qs < 2; ++qs)
#pragma unroll
    for (int ks = 0; ks < 4; ++ks)
      qf[qs][ks] = *(const short8*)(Qb + (size_t)(b*NS + q0 + qs*32 + l31)*ND + h*64 + ks*16 + hi*8);

  f32x16 oacc[2][2] = {};    // [qs][dblk]; C rows q=(r&3)+8(r>>2)+4hi, col d=dblk*32+l31
  float lsum[2] = {0.f, 0.f};

  auto stage = [&](int t, int bu) {
#pragma unroll
    for (int p = 0; p < 2; ++p) {
      gload16(Kp[p] + (size_t)t*64*ND, &Kt[bu][dofs[p]]);
      gload16(Vp[p] + t*64,            &Vt[bu][dofs[p]]);
    }
  };

  auto tile = [&](int bu) {
    const char* Kc = (const char*)&Kt[bu][0];
    const char* Vc = (const char*)&Vt[bu][0];
    short8 pa[2][2][2];      // [qs][n][ksl]
    float rs[2] = {0.f, 0.f};
#pragma unroll
    for (int n = 0; n < 2; ++n) {
      f32x16 st[2] = {};
      const int r = n*32 + l31;
      __builtin_amdgcn_s_setprio(1);
#pragma unroll
      for (int ks = 0; ks < 4; ++ks) {
        short8 kf = *(const short8*)(Kc + (((2*ks + hi) << 10) + r*16));
        st[0] = __builtin_amdgcn_mfma_f32_32x32x16_bf16(kf, qf[0][ks], st[0], 0, 0, 0);
        st[1] = __builtin_amdgcn_mfma_f32_32x32x16_bf16(kf, qf[1][ks], st[1], 0, 0, 0);
      }
      __builtin_amdgcn_s_setprio(0);
#pragma unroll
      for (int qs = 0; qs < 2; ++qs) {
        float lrs = 0.f;
#pragma unroll
        for (int e = 0; e < 16; ++e) {
          float p = __builtin_amdgcn_exp2f(st[qs][e]);
          st[qs][e] = p;
          lrs += p;
        }
        rs[qs] += lrs;
        uint32_t w[4][2];
#pragma unroll
        for (int e = 0; e < 4; ++e) {
          asm("v_cvt_pk_bf16_f32 %0, %1, %2"
              : "=v"(w[e][0]) : "v"(st[qs][4*e+0]), "v"(st[qs][4*e+1]));
          asm("v_cvt_pk_bf16_f32 %0, %1, %2"
              : "=v"(w[e][1]) : "v"(st[qs][4*e+2]), "v"(st[qs][4*e+3]));
        }
#pragma unroll
        for (int ksl = 0; ksl < 2; ++ksl) {
          uint32_t a0 = w[2*ksl][0], b0 = w[2*ksl+1][0];
          uint32_t a1 = w[2*ksl][1], b1 = w[2*ksl+1][1];
          asm("v_permlane32_swap_b32 %0, %1" : "+v"(a0), "+v"(b0));
          asm("v_permlane32_swap_b32 %0, %1" : "+v"(a1), "+v"(b1));
          union { uint32_t u[4]; short8 s; } f;
          f.u[0] = a0; f.u[1] = a1; f.u[2] = b0; f.u[3] = b1;
          pa[qs][n][ksl] = f.s;
        }
      }
    }
#pragma unroll
    for (int qs = 0; qs < 2; ++qs) {
      rs[qs] += __shfl_xor(rs[qs], 32);
      lsum[qs] += rs[qs];
    }

    __builtin_amdgcn_s_setprio(1);
#pragma unroll
    for (int d = 0; d < 2; ++d) {
      const int dr = d*32 + l31;
#pragma unroll
      for (int n = 0; n < 2; ++n)
#pragma unroll
        for (int ksl = 0; ksl < 2; ++ksl) {
          const int g = n*4 + ksl*2 + hi;
          short8 vf = *(const short8*)(Vc + ((g << 10) + dr*16));
          oacc[0][d] = __builtin_amdgcn_mfma_f32_32x32x16_bf16(pa[0][n][ksl], vf, oacc[0][d], 0, 0, 0);
          oacc[1][d] = __builtin_amdgcn_mfma_f32_32x32x16_bf16(pa[1][n][ksl], vf, oacc[1][d], 0, 0, 0);
        }
    }
    __builtin_amdgcn_s_setprio(0);
  };

  // prologue: stage tiles 0,1; wait tile 0 only (tile 1's 4 loads may fly)
  stage(0, 0);
  stage(1, 1);
  asm volatile("s_waitcnt vmcnt(4)" ::: "memory");
  __builtin_amdgcn_s_barrier();

  int bu = 0;
  for (int t = 0; t < 30; ++t) {
    int nb = bu + 2; if (nb >= 3) nb -= 3;
    stage(t + 2, nb);
    tile(bu);
    // wait own t+1 loads (leave t+2's 4 in flight), then block-wide barrier
    asm volatile("s_waitcnt vmcnt(4)" ::: "memory");
    __builtin_amdgcn_s_barrier();
    bu = (bu + 1 == 3) ? 0 : bu + 1;
  }
  tile(bu);                                          // t = 30
  asm volatile("s_waitcnt vmcnt(0)" ::: "memory");   // tile 31 fully landed
  __builtin_amdgcn_s_barrier();
  bu = (bu + 1 == 3) ? 0 : bu + 1;
  tile(bu);                                          // t = 31

  // ---- epilogue ----
#pragma unroll
  for (int qs = 0; qs < 2; ++qs) {
    float linv[16];
#pragma unroll
    for (int r = 0; r < 16; ++r)
      linv[r] = 1.0f / __shfl(lsum[qs], (r & 3) + 8*(r >> 2) + 4*hi);
#pragma unroll
    for (int d = 0; d < 2; ++d)
#pragma unroll
      for (int r = 0; r < 16; ++r) {
        int qrow = q0 + qs*32 + (r & 3) + 8*(r >> 2) + 4*hi;
        O[(size_t)(b*NS + qrow)*ND + h*64 + d*32 + l31] = f2bf(oacc[qs][d][r] * linv[r]);
      }
  }
}

// ---------------- launch ----------------
extern "C" void kernel_launch(void* const* d_in, const int* in_sizes, int n_in,
                              void* d_out, int out_size, void* d_ws, size_t ws_size,
                              hipStream_t stream) {
  const float* q  = (const float*)d_in[0];
  const float* k  = (const float*)d_in[1];
  const float* v  = (const float*)d_in[2];
  const float* wq = (const float*)d_in[3];
  const float* wk = (const float*)d_in[4];
  const float* wv = (const float*)d_in[5];
  const float* wo = (const float*)d_in[6];

  unsigned short* Wq = (unsigned short*)d_ws;
  unsigned short* Wk = Wq + (size_t)ND*ND;
  unsigned short* Wv = Wk + (size_t)ND*ND;
  unsigned short* Wo = Wv + (size_t)ND*ND;
  unsigned short* Xq = Wo + (size_t)ND*ND;
  unsigned short* Xk = Xq + (size_t)NM*ND;
  unsigned short* Xv = Xk + (size_t)NM*ND;
  unsigned short* Qb = Xv + (size_t)NM*ND;
  unsigned short* Kb = Qb + (size_t)NM*ND;
  unsigned short* VbT = (unsigned short*)d_out;   // scratch in d_out; rewritten by gemm_o
  unsigned short* Ob  = Xq;                       // alias: Xq dead after qkv launch

  convert_all<<<dim3(NM*ND/(256*8), 4), 256, 0, stream>>>(
      q, k, v, wq, wk, wv, wo, Xq, Xk, Xv, Wq, Wk, Wv, Wo);

  gemm_qkv<<<dim3(4, 32, 3), 512, 0, stream>>>(Xq, Wq, Qb, Xk, Wk, Kb, Xv, Wv, VbT);

  flash_attn<<<dim3(8, 64), 256, 0, stream>>>(Qb, Kb, VbT, Ob);

  gemm_o<<<dim3(8, 32), 512, 0, stream>>>(Ob, Wo, (float*)d_out);
}